// Round 26
// baseline (1517.625 us; speedup 1.0000x reference)
//
#include <hip/hip_runtime.h>

typedef unsigned short u16;
typedef unsigned int u32;
typedef unsigned long long u64;
typedef __attribute__((ext_vector_type(4))) float f32x4;
typedef __attribute__((ext_vector_type(8))) short s16x8;

__device__ __forceinline__ float bf2f(u16 u) {
  union { u32 i; float f; } x;
  x.i = ((u32)u) << 16;
  return x.f;
}
__device__ __forceinline__ u16 f2bf(float f) {
  union { float f; u32 i; } u;
  u.f = f;
  u32 r = u.i + 0x7fffu + ((u.i >> 16) & 1u);
  return (u16)(r >> 16);
}

static inline int nblkH(long long n) { return (int)((n + 255) / 256); }

// identifier-named symbol; generic zero-fill
__global__ void HeteroGraphSAGE_52931176955955_kernel(float* p, long long n) {
  long long i = (long long)blockIdx.x * 256 + threadIdx.x;
  if (i < n) p[i] = 0.0f;
}

// ---------------- weight prep: 25 bf16 W^T mats (n-major) ----------------
__global__ void g_wprep(const float* Wl, const float* Wr, u16* wt, int total) {
  int idx = blockIdx.x * 256 + threadIdx.x;
  if (idx >= total) return;
  int w = idx >> 14;
  int r = idx & 16383;
  int n = r >> 7, k = r & 127;
  float v;
  if (w < 11) v = Wl[w * 16384 + k * 128 + n];
  else if (w < 22) v = Wr[(w - 11) * 16384 + k * 128 + n];
  else {
    int a = (w == 22) ? 2 : (w == 23) ? 6 : 7;
    int b = (w == 22) ? 4 : (w == 23) ? 8 : 10;
    v = Wr[a * 16384 + k * 128 + n] + Wr[b * 16384 + k * 128 + n];
  }
  wt[idx] = f2bf(v);
}

__global__ void g_bprep(const float* bL, float* cb) {
  int c = threadIdx.x;  // 128
  cb[c]       = bL[2 * 128 + c] + bL[4 * 128 + c];
  cb[128 + c] = bL[6 * 128 + c] + bL[8 * 128 + c];
  cb[256 + c] = bL[7 * 128 + c] + bL[10 * 128 + c];
}

__global__ void g_cvt(const float* x, u16* o, long long n4) {
  long long i = (long long)blockIdx.x * 256 + threadIdx.x;
  if (i >= n4) return;
  f32x4 v = *(const f32x4*)(x + (i << 2));
  u64 p = ((u64)f2bf(v.x)) | (((u64)f2bf(v.y)) << 16) |
          (((u64)f2bf(v.z)) << 32) | (((u64)f2bf(v.w)) << 48);
  *(u64*)(o + (i << 2)) = p;
}

// ---------------- batched CSR build (all 5 edge types at once) ----------------
struct Seg { const int* e; int E; int eoff; int roff; };

__device__ __forceinline__ Seg pick_seg(Seg s0, Seg s1, Seg s2, Seg s3, Seg s4, int w) {
  if (w >= s4.eoff) return s4;
  if (w >= s3.eoff) return s3;
  if (w >= s2.eoff) return s2;
  if (w >= s1.eoff) return s1;
  return s0;
}

__global__ void g_deg5(Seg s0, Seg s1, Seg s2, Seg s3, Seg s4, int Eall, int* deg) {
  int w = blockIdx.x * 256 + threadIdx.x;
  if (w >= Eall) return;
  Seg s = pick_seg(s0, s1, s2, s3, s4, w);
  int i = w - s.eoff;
  atomicAdd(deg + s.roff + s.e[s.E + i], 1);
}

__global__ void g_fill5(Seg s0, Seg s1, Seg s2, Seg s3, Seg s4, int Eall,
                        int* cur, int* col) {
  int w = blockIdx.x * 256 + threadIdx.x;
  if (w >= Eall) return;
  Seg s = pick_seg(s0, s1, s2, s3, s4, w);
  int i = w - s.eoff;
  int src = s.e[i];
  int d = s.e[s.E + i];
  col[atomicAdd(cur + s.roff + d, 1)] = src;
}

__global__ void g_bsum(const int* deg, int n, int C, int* bsum) {
  __shared__ int ws[4];
  int b = blockIdx.x, tid = threadIdx.x;
  int lane = tid & 63, wv = tid >> 6;
  int lo = b * C, hi = lo + C; if (hi > n) hi = n;
  int s = 0;
  for (int i = lo + tid; i < hi; i += 256) s += deg[i];
  for (int o = 32; o > 0; o >>= 1) s += __shfl_down(s, o);
  if (lane == 0) ws[wv] = s;
  __syncthreads();
  if (tid == 0) bsum[b] = ws[0] + ws[1] + ws[2] + ws[3];
}

__global__ void g_scan_write(const int* deg, int n, int C, const int* bsum,
                             int* rp, int* cur) {
  __shared__ int ws[4];
  __shared__ int bc;
  int b = blockIdx.x, tid = threadIdx.x;
  int lane = tid & 63, wv = tid >> 6;

  int v = bsum[tid];
  int s = (tid < b) ? v : 0;
  for (int o = 32; o > 0; o >>= 1) s += __shfl_down(s, o);
  if (lane == 0) ws[wv] = s;
  __syncthreads();
  if (tid == 0) bc = ws[0] + ws[1] + ws[2] + ws[3];
  __syncthreads();
  int base = bc;

  if (b == 0) {
    __syncthreads();
    int t = v;
    for (int o = 32; o > 0; o >>= 1) t += __shfl_down(t, o);
    if (lane == 0) ws[wv] = t;
    __syncthreads();
    if (tid == 0) rp[n] = ws[0] + ws[1] + ws[2] + ws[3];
  }

  int lo = b * C, hi = lo + C; if (hi > n) hi = n;
  for (int t0 = lo; t0 < hi; t0 += 256) {
    int i = t0 + tid;
    int d = (i < hi) ? deg[i] : 0;
    int x = d;
    for (int o = 1; o < 64; o <<= 1) {
      int t = __shfl_up(x, o);
      if (lane >= o) x += t;
    }
    __syncthreads();
    if (lane == 63) ws[wv] = x;
    __syncthreads();
    int wadd = 0;
    if (wv > 0) wadd += ws[0];
    if (wv > 1) wadd += ws[1];
    if (wv > 2) wadd += ws[2];
    int excl = x + wadd - d;
    if (i < hi) {
      rp[i] = base + excl;
      cur[i] = base + excl;
    }
    base += ws[0] + ws[1] + ws[2] + ws[3];
    __syncthreads();
  }
}

// ---------------- fused (dual-edge) gather + transform + MFMA SAGE ----------------
// 32-row tiles; neighbor tiles staged in LDS (round-19 gather); ROOT read
// directly from global in the MFMA phase (no LDS) -> dual LDS 17.4KB, 8 blk/CU.
__device__ __forceinline__ void stage_store(u16* sm, int rr, int q, const float* acc) {
  s16x8 o;
#pragma unroll
  for (int e = 0; e < 8; ++e) o[e] = (short)f2bf(acc[e]);
  int byte = (rr << 8) + (q << 4);
  int swz = byte ^ ((rr & 7) << 4);
  *(s16x8*)((char*)sm + swz) = o;
}

__global__ __launch_bounds__(256) void g_sage(
    const int* rpA, const int* colA, const u16* srcA, const float* scshA, const u16* wtlA,
    const int* rpB, const int* colB, const u16* srcB, const float* scshB, const u16* wtlB,
    const void* root, int root_f32, const float* scshR, const u16* wtr,
    const float* bias, void* out, int out_bf, int N, float* partial) {
  extern __shared__ __align__(16) char smem[];
  const int tid = threadIdx.x;
  const int r0 = blockIdx.x * 32;
  const int nA = 1 + (rpB ? 1 : 0);
  u16* smA = (u16*)smem;
  u16* smB = (u16*)(smem + 8192);
  float* bs = (float*)(smem + (size_t)nA * 8192);
  if (partial) bs[tid] = 0.f;

  for (int i = tid; i < nA * 512; i += 256) {
    int region = i >> 9;
    int t = i & 511;
    int rr = t >> 4, q = t & 15;
    int row = r0 + rr;
    int c0 = q * 8;
    float acc[8];
#pragma unroll
    for (int e = 0; e < 8; ++e) acc[e] = 0.f;

    const int* rp = (region == 0) ? rpA : rpB;
    const int* col = (region == 0) ? colA : colB;
    const u16* src = (region == 0) ? srcA : srcB;
    const float* scsh = (region == 0) ? scshA : scshB;
    if (row < N) {
      int j0 = rp[row], j1 = rp[row + 1];
      if (scsh) {
        float sc[8], sh[8];
#pragma unroll
        for (int e = 0; e < 8; ++e) { sc[e] = scsh[c0 + e]; sh[e] = scsh[128 + c0 + e]; }
        if (j0 < j1) {
          s16x8 vc = *(const s16x8*)(src + (size_t)col[j0] * 128 + c0);
          for (int j = j0 + 1; j < j1; ++j) {
            s16x8 vn = *(const s16x8*)(src + (size_t)col[j] * 128 + c0);
#pragma unroll
            for (int e = 0; e < 8; ++e)
              acc[e] += fmaxf(bf2f((u16)vc[e]), 0.f) * sc[e] + sh[e];
            vc = vn;
          }
#pragma unroll
          for (int e = 0; e < 8; ++e)
            acc[e] += fmaxf(bf2f((u16)vc[e]), 0.f) * sc[e] + sh[e];
        }
      } else {
        if (j0 < j1) {
          s16x8 vc = *(const s16x8*)(src + (size_t)col[j0] * 128 + c0);
          for (int j = j0 + 1; j < j1; ++j) {
            s16x8 vn = *(const s16x8*)(src + (size_t)col[j] * 128 + c0);
#pragma unroll
            for (int e = 0; e < 8; ++e) acc[e] += bf2f((u16)vc[e]);
            vc = vn;
          }
#pragma unroll
          for (int e = 0; e < 8; ++e) acc[e] += bf2f((u16)vc[e]);
        }
      }
      float inv = 1.0f / fmaxf((float)(j1 - j0), 1.0f);
#pragma unroll
      for (int e = 0; e < 8; ++e) acc[e] *= inv;
    }
    stage_store((region == 0) ? smA : smB, rr, q, acc);
  }
  __syncthreads();

  // ---- MFMA: wave wv -> row-tile m=wv>>1, col-tiles nq..nq+3 ----
  const int lane = tid & 63;
  const int wv = tid >> 6;
  const int mi = lane & 15;
  const int kg = lane >> 4;
  const int m = wv >> 1;
  const int nq = (wv & 1) * 4;
  const int arow = m * 16 + mi;
  const int abase = arow << 8;
  const int amask = (arow & 7) << 4;
  const int rrow = r0 + arow;  // global row for the A-fragment (and root)

  f32x4 acc4[4];
#pragma unroll
  for (int t = 0; t < 4; ++t) acc4[t] = (f32x4){0.f, 0.f, 0.f, 0.f};

#pragma unroll
  for (int kt = 0; kt < 4; ++kt) {
    int k0 = kt * 32 + kg * 8;
    int off = (abase + (k0 << 1)) ^ amask;
    s16x8 afA = *(const s16x8*)((const char*)smA + off);
    s16x8 afB, afR;
    if (rpB) afB = *(const s16x8*)((const char*)smB + off);
    if (root) {
      float a[8];
      if (rrow < N) {
        if (root_f32) {
          const float* rp_ = (const float*)root + (size_t)rrow * 128 + k0;
          f32x4 lo = *(const f32x4*)rp_;
          f32x4 hi = *(const f32x4*)(rp_ + 4);
          a[0] = lo.x; a[1] = lo.y; a[2] = lo.z; a[3] = lo.w;
          a[4] = hi.x; a[5] = hi.y; a[6] = hi.z; a[7] = hi.w;
        } else {
          s16x8 v = *(const s16x8*)((const u16*)root + (size_t)rrow * 128 + k0);
#pragma unroll
          for (int e = 0; e < 8; ++e) a[e] = bf2f((u16)v[e]);
        }
        if (scshR) {
#pragma unroll
          for (int e = 0; e < 8; ++e)
            a[e] = fmaxf(a[e], 0.f) * scshR[k0 + e] + scshR[128 + k0 + e];
        }
      } else {
#pragma unroll
        for (int e = 0; e < 8; ++e) a[e] = 0.f;
      }
#pragma unroll
      for (int e = 0; e < 8; ++e) afR[e] = (short)f2bf(a[e]);
    }
#pragma unroll
    for (int t = 0; t < 4; ++t) {
      int cr = (nq + t) * 16 + mi;
      s16x8 b = *(const s16x8*)(wtlA + cr * 128 + k0);
      acc4[t] = __builtin_amdgcn_mfma_f32_16x16x32_bf16(afA, b, acc4[t], 0, 0, 0);
      if (rpB) {
        s16x8 b2 = *(const s16x8*)(wtlB + cr * 128 + k0);
        acc4[t] = __builtin_amdgcn_mfma_f32_16x16x32_bf16(afB, b2, acc4[t], 0, 0, 0);
      }
      if (root) {
        s16x8 b3 = *(const s16x8*)(wtr + cr * 128 + k0);
        acc4[t] = __builtin_amdgcn_mfma_f32_16x16x32_bf16(afR, b3, acc4[t], 0, 0, 0);
      }
    }
  }

  // ---- epilogue: C/D col=lane&15, row=(lane>>4)*4+reg [m89]; fused BN stats ----
  int rbase = (lane >> 4) << 2;
#pragma unroll
  for (int t = 0; t < 4; ++t) {
    int c = (nq + t) * 16 + mi;
    float bb = bias[c];
    float s = 0.f, q = 0.f;
#pragma unroll
    for (int reg = 0; reg < 4; ++reg) {
      int row = r0 + m * 16 + rbase + reg;
      if (row < N) {
        size_t o = (size_t)row * 128 + c;
        float v = acc4[t][reg] + bb;
        if (out_bf) ((u16*)out)[o] = f2bf(v);
        else        ((float*)out)[o] = v;
        if (partial) {
          float r = fmaxf(v, 0.f);
          s += r;
          q += r * r;
        }
      }
    }
    if (partial) {
      s += __shfl_xor(s, 16); s += __shfl_xor(s, 32);
      q += __shfl_xor(q, 16); q += __shfl_xor(q, 32);
      if (kg == 0) {
        atomicAdd(&bs[c], s);
        atomicAdd(&bs[128 + c], q);
      }
    }
  }
  if (partial) {
    __syncthreads();
    partial[(size_t)blockIdx.x * 256 + tid] = bs[tid];
  }
}

// ---------------- BN finalize: 2-stage partial reduce ----------------
__global__ void g_bnred(const float* partial, int nb, float* p2) {
  int tid = threadIdx.x;  // 256
  float acc = 0.f;
  for (int blk = blockIdx.x; blk < nb; blk += 64)
    acc += partial[(size_t)blk * 256 + tid];
  p2[(size_t)blockIdx.x * 256 + tid] = acc;
}

__global__ void g_bnfin(const float* p2, const float* g, const float* b,
                        float invN, float* scsh) {
  int c = threadIdx.x;  // 128
  float s = 0.f, q = 0.f;
  for (int blk = 0; blk < 64; ++blk) {
    s += p2[(size_t)blk * 256 + c];
    q += p2[(size_t)blk * 256 + 128 + c];
  }
  float m = s * invN;
  float v = q * invN - m * m;
  float sc = rsqrtf(v + 1e-5f) * g[c];
  scsh[c] = sc;
  scsh[128 + c] = b[c] - m * sc;
}

// ---------------- host ----------------
struct Csr { int* rp; int* col; };

static void bn_vH(int nb, const float* g, const float* b, int n,
                  float* partial, float* p2, float* scsh, hipStream_t st) {
  g_bnred<<<64, 256, 0, st>>>(partial, nb, p2);
  g_bnfin<<<1, 128, 0, st>>>(p2, g, b, 1.0f / (float)n, scsh);
}

extern "C" void kernel_launch(void* const* d_in, const int* in_sizes, int n_in,
                              void* d_out, int out_size, void* d_ws, size_t ws_size,
                              hipStream_t stream) {
  const float* x_paper  = (const float*)d_in[0];
  const float* x_author = (const float*)d_in[1];
  const int* e_pp = (const int*)d_in[3];
  const int* e_pa = (const int*)d_in[4];
  const int* e_ap = (const int*)d_in[5];
  const int* e_ai = (const int*)d_in[6];
  const int* e_ia = (const int*)d_in[7];
  const float* Wl  = (const float*)d_in[8];
  const float* bL  = (const float*)d_in[9];
  const float* Wr  = (const float*)d_in[10];
  const float* bng = (const float*)d_in[11];
  const float* bnb = (const float*)d_in[12];

  const int NP = in_sizes[0] / 128;
  const int NA = in_sizes[1] / 128;
  const int NI = in_sizes[2] / 128;
  const int Epp = in_sizes[3] / 2;
  const int Epa = in_sizes[4] / 2;
  const int Eap = in_sizes[5] / 2;
  const int Eai = in_sizes[6] / 2;
  const int Eia = in_sizes[7] / 2;

  const int nbP = (NP + 31) / 32;
  const int nbA = (NA + 31) / 32;
  const int nbI = (NI + 31) / 32;

  const int R = 2 * NP + 2 * NA + NI;
  const long long Eall = (long long)Epp + Epa + Eap + Eai + Eia;

  // ws (~170 MB)
  char* ws = (char*)d_ws;
  size_t off = 0;
  u16* xp   = (u16*)(ws + off);   off += (size_t)NP * 256;
  u16* h_p1 = (u16*)(ws + off);   off += (size_t)NP * 256;
  u16* h_a1 = (u16*)(ws + off);   off += (size_t)NA * 256;
  u16* wt   = (u16*)(ws + off);   off += (size_t)25 * 16384 * 2;
  int* rp_all  = (int*)(ws + off);   off += (size_t)(R + 1) * 4;
  int* col_all = (int*)(ws + off);   off += (size_t)Eall * 4;
  int* dega    = (int*)(ws + off);   off += (size_t)R * 4;
  int* cur     = (int*)(ws + off);   off += (size_t)R * 4;
  int* bsum    = (int*)(ws + off);   off += 1024;
  float* partial = (float*)(ws + off); off += (size_t)nbP * 1024;
  float* p2    = (float*)(ws + off); off += 64 * 1024;
  float* scsh0 = (float*)(ws + off); off += 1024;
  float* scsh1 = (float*)(ws + off); off += 1024;
  float* scsh2 = (float*)(ws + off); off += 1024;
  float* scsh3 = (float*)(ws + off); off += 1024;
  float* scsh4 = (float*)(ws + off); off += 1024;
  float* cb    = (float*)(ws + off); off += 3 * 512;

  Csr cpp; cpp.rp = rp_all;                      cpp.col = col_all;
  Csr cpa; cpa.rp = rp_all + NP;                 cpa.col = col_all;
  Csr cap; cap.rp = rp_all + NP + NA;            cap.col = col_all;
  Csr cai; cai.rp = rp_all + 2 * NP + NA;        cai.col = col_all;
  Csr cia; cia.rp = rp_all + 2 * NP + NA + NI;   cia.col = col_all;

  float* outp = (float*)d_out;
  float* outa = outp + (size_t)NP * 128;
  float* outi = outa + (size_t)NA * 128;
  u16* h_p0 = (u16*)outp;
  u16* h_a0 = (u16*)outa;
  u16* h_i1 = (u16*)outp + (size_t)NP * 128;

  g_wprep<<<nblkH(25 * 16384), 256, 0, stream>>>(Wl, Wr, wt, 25 * 16384);
  g_bprep<<<1, 128, 0, stream>>>(bL, cb);
  g_cvt<<<nblkH((long long)NP * 32), 256, 0, stream>>>(x_paper, xp, (long long)NP * 32);

  Seg s0 = { e_pp, Epp, 0, 0 };
  Seg s1 = { e_pa, Epa, Epp, NP };
  Seg s2 = { e_ap, Eap, Epp + Epa, NP + NA };
  Seg s3 = { e_ai, Eai, Epp + Epa + Eap, 2 * NP + NA };
  Seg s4 = { e_ia, Eia, Epp + Epa + Eap + Eai, 2 * NP + NA + NI };
  HeteroGraphSAGE_52931176955955_kernel<<<nblkH(R), 256, 0, stream>>>((float*)dega, R);
  g_deg5<<<nblkH(Eall), 256, 0, stream>>>(s0, s1, s2, s3, s4, (int)Eall, dega);
  int C = (R + 255) / 256;
  g_bsum<<<256, 256, 0, stream>>>(dega, R, C, bsum);
  g_scan_write<<<256, 256, 0, stream>>>(dega, R, C, bsum, rp_all, cur);
  g_fill5<<<nblkH(Eall), 256, 0, stream>>>(s0, s1, s2, s3, s4, (int)Eall, cur, col_all);

  const float* nof = (const float*)0;
  const int* noi = (const int*)0;
  const u16* nou = (const u16*)0;
  float* nop = (float*)0;

#define WT(i) (wt + (size_t)(i) * 16384)

  // ---- Layer 0 (raw hidden + fused BN stats) ----
  g_sage<<<nbP, 256, 1 * 8192 + 1024, stream>>>(
      cpp.rp, cpp.col, xp, nof, WT(0), noi, noi, nou, nof, nou,
      xp, 0, nof, WT(11), bL + 0 * 128, h_p0, 1, NP, partial);
  bn_vH(nbP, bng + 0 * 128, bnb + 0 * 128, NP, partial, p2, scsh0, stream);
  g_sage<<<nbA, 256, 1 * 8192 + 1024, stream>>>(
      cpa.rp, cpa.col, xp, nof, WT(1), noi, noi, nou, nof, nou,
      x_author, 1, nof, WT(12), bL + 1 * 128, h_a0, 1, NA, partial);
  bn_vH(nbA, bng + 1 * 128, bnb + 1 * 128, NA, partial, p2, scsh1, stream);

  // ---- Layer 1 ----
  g_sage<<<nbP, 256, 2 * 8192 + 1024, stream>>>(          // p1 = pp + ap (dual)
      cpp.rp, cpp.col, h_p0, scsh0, WT(2), cap.rp, cap.col, h_a0, scsh1, WT(4),
      h_p0, 0, scsh0, WT(22), cb, h_p1, 1, NP, partial);
  bn_vH(nbP, bng + 2 * 128, bnb + 2 * 128, NP, partial, p2, scsh2, stream);
  g_sage<<<nbA, 256, 1 * 8192 + 1024, stream>>>(          // a1 = pa
      cpa.rp, cpa.col, h_p0, scsh0, WT(3), noi, noi, nou, nof, nou,
      h_a0, 0, scsh1, WT(14), bL + 3 * 128, h_a1, 1, NA, partial);
  bn_vH(nbA, bng + 3 * 128, bnb + 3 * 128, NA, partial, p2, scsh3, stream);
  g_sage<<<nbI, 256, 1 * 8192 + 1024, stream>>>(          // i1 = ai (no root)
      cai.rp, cai.col, h_a0, scsh1, WT(5), noi, noi, nou, nof, nou,
      (const void*)0, 0, nof, nou, bL + 5 * 128, h_i1, 1, NI, partial);
  bn_vH(nbI, bng + 4 * 128, bnb + 4 * 128, NI, partial, p2, scsh4, stream);

  // ---- Layer 2 (order: a2, i2, then p2 — p2 clobbers h_i1's region) ----
  g_sage<<<nbA, 256, 2 * 8192 + 1024, stream>>>(          // a2 = pa + ia (dual)
      cpa.rp, cpa.col, h_p1, scsh2, WT(7), cia.rp, cia.col, h_i1, scsh4, WT(10),
      h_a1, 0, scsh3, WT(24), cb + 256, outa, 0, NA, nop);
  g_sage<<<nbI, 256, 1 * 8192 + 1024, stream>>>(          // i2 = ai
      cai.rp, cai.col, h_a1, scsh3, WT(9), noi, noi, nou, nof, nou,
      h_i1, 0, scsh4, WT(20), bL + 9 * 128, outi, 0, NI, nop);
  g_sage<<<nbP, 256, 2 * 8192 + 1024, stream>>>(          // p2 = pp + ap (dual)
      cpp.rp, cpp.col, h_p1, scsh2, WT(6), cap.rp, cap.col, h_a1, scsh3, WT(8),
      h_p1, 0, scsh2, WT(23), cb + 128, outp, 0, NP, nop);

#undef WT
  (void)n_in; (void)ws_size; (void)out_size;
}

// Round 27
// 1425.600 us; speedup vs baseline: 1.0646x; 1.0646x over previous
//
#include <hip/hip_runtime.h>

typedef unsigned short u16;
typedef unsigned int u32;
typedef unsigned long long u64;
typedef __attribute__((ext_vector_type(4))) float f32x4;
typedef __attribute__((ext_vector_type(8))) short s16x8;

__device__ __forceinline__ float bf2f(u16 u) {
  union { u32 i; float f; } x;
  x.i = ((u32)u) << 16;
  return x.f;
}
__device__ __forceinline__ u16 f2bf(float f) {
  union { float f; u32 i; } u;
  u.f = f;
  u32 r = u.i + 0x7fffu + ((u.i >> 16) & 1u);
  return (u16)(r >> 16);
}

static inline int nblkF(long long n) { return (int)((n + 255) / 256); }

// identifier-named symbol; generic zero-fill
__global__ void HeteroGraphSAGE_52931176955955_kernel(float* p, long long n) {
  long long i = (long long)blockIdx.x * 256 + threadIdx.x;
  if (i < n) p[i] = 0.0f;
}

// ---------------- weight prep: 25 bf16 W^T mats (n-major) ----------------
__global__ void g_wprep(const float* Wl, const float* Wr, u16* wt, int total) {
  int idx = blockIdx.x * 256 + threadIdx.x;
  if (idx >= total) return;
  int w = idx >> 14;
  int r = idx & 16383;
  int n = r >> 7, k = r & 127;
  float v;
  if (w < 11) v = Wl[w * 16384 + k * 128 + n];
  else if (w < 22) v = Wr[(w - 11) * 16384 + k * 128 + n];
  else {
    int a = (w == 22) ? 2 : (w == 23) ? 6 : 7;
    int b = (w == 22) ? 4 : (w == 23) ? 8 : 10;
    v = Wr[a * 16384 + k * 128 + n] + Wr[b * 16384 + k * 128 + n];
  }
  wt[idx] = f2bf(v);
}

__global__ void g_bprep(const float* bL, float* cb) {
  int c = threadIdx.x;  // 128
  cb[c]       = bL[2 * 128 + c] + bL[4 * 128 + c];
  cb[128 + c] = bL[6 * 128 + c] + bL[8 * 128 + c];
  cb[256 + c] = bL[7 * 128 + c] + bL[10 * 128 + c];
}

__global__ void g_cvt(const float* x, u16* o, long long n4) {
  long long i = (long long)blockIdx.x * 256 + threadIdx.x;
  if (i >= n4) return;
  f32x4 v = *(const f32x4*)(x + (i << 2));
  u64 p = ((u64)f2bf(v.x)) | (((u64)f2bf(v.y)) << 16) |
          (((u64)f2bf(v.z)) << 32) | (((u64)f2bf(v.w)) << 48);
  *(u64*)(o + (i << 2)) = p;
}

// ---------------- batched CSR build (all 5 edge types at once) ----------------
struct Seg { const int* e; int E; int eoff; int roff; };

__device__ __forceinline__ Seg pick_seg(Seg s0, Seg s1, Seg s2, Seg s3, Seg s4, int w) {
  if (w >= s4.eoff) return s4;
  if (w >= s3.eoff) return s3;
  if (w >= s2.eoff) return s2;
  if (w >= s1.eoff) return s1;
  return s0;
}

__global__ void g_deg5(Seg s0, Seg s1, Seg s2, Seg s3, Seg s4, int Eall, int* deg) {
  int w = blockIdx.x * 256 + threadIdx.x;
  if (w >= Eall) return;
  Seg s = pick_seg(s0, s1, s2, s3, s4, w);
  int i = w - s.eoff;
  atomicAdd(deg + s.roff + s.e[s.E + i], 1);
}

__global__ void g_fill5(Seg s0, Seg s1, Seg s2, Seg s3, Seg s4, int Eall,
                        int* cur, int* col) {
  int w = blockIdx.x * 256 + threadIdx.x;
  if (w >= Eall) return;
  Seg s = pick_seg(s0, s1, s2, s3, s4, w);
  int i = w - s.eoff;
  int src = s.e[i];
  int d = s.e[s.E + i];
  col[atomicAdd(cur + s.roff + d, 1)] = src;
}

__global__ void g_bsum(const int* deg, int n, int C, int* bsum) {
  __shared__ int ws[4];
  int b = blockIdx.x, tid = threadIdx.x;
  int lane = tid & 63, wv = tid >> 6;
  int lo = b * C, hi = lo + C; if (hi > n) hi = n;
  int s = 0;
  for (int i = lo + tid; i < hi; i += 256) s += deg[i];
  for (int o = 32; o > 0; o >>= 1) s += __shfl_down(s, o);
  if (lane == 0) ws[wv] = s;
  __syncthreads();
  if (tid == 0) bsum[b] = ws[0] + ws[1] + ws[2] + ws[3];
}

__global__ void g_scan_write(const int* deg, int n, int C, const int* bsum,
                             int* rp, int* cur) {
  __shared__ int ws[4];
  __shared__ int bc;
  int b = blockIdx.x, tid = threadIdx.x;
  int lane = tid & 63, wv = tid >> 6;

  int v = bsum[tid];
  int s = (tid < b) ? v : 0;
  for (int o = 32; o > 0; o >>= 1) s += __shfl_down(s, o);
  if (lane == 0) ws[wv] = s;
  __syncthreads();
  if (tid == 0) bc = ws[0] + ws[1] + ws[2] + ws[3];
  __syncthreads();
  int base = bc;

  if (b == 0) {
    __syncthreads();
    int t = v;
    for (int o = 32; o > 0; o >>= 1) t += __shfl_down(t, o);
    if (lane == 0) ws[wv] = t;
    __syncthreads();
    if (tid == 0) rp[n] = ws[0] + ws[1] + ws[2] + ws[3];
  }

  int lo = b * C, hi = lo + C; if (hi > n) hi = n;
  for (int t0 = lo; t0 < hi; t0 += 256) {
    int i = t0 + tid;
    int d = (i < hi) ? deg[i] : 0;
    int x = d;
    for (int o = 1; o < 64; o <<= 1) {
      int t = __shfl_up(x, o);
      if (lane >= o) x += t;
    }
    __syncthreads();
    if (lane == 63) ws[wv] = x;
    __syncthreads();
    int wadd = 0;
    if (wv > 0) wadd += ws[0];
    if (wv > 1) wadd += ws[1];
    if (wv > 2) wadd += ws[2];
    int excl = x + wadd - d;
    if (i < hi) {
      rp[i] = base + excl;
      cur[i] = base + excl;
    }
    base += ws[0] + ws[1] + ws[2] + ws[3];
    __syncthreads();
  }
}

// ---------------- fused (dual-edge) gather + transform + MFMA SAGE ----------------
// (round-19 structure: per-(row,chunk) tasks, 2-deep pipeline — proven best)
__device__ __forceinline__ void stage_store(u16* sm, int rr, int q, const float* acc) {
  s16x8 o;
#pragma unroll
  for (int e = 0; e < 8; ++e) o[e] = (short)f2bf(acc[e]);
  int byte = (rr << 8) + (q << 4);
  int swz = byte ^ ((rr & 7) << 4);
  *(s16x8*)((char*)sm + swz) = o;
}

__global__ __launch_bounds__(256) void g_sage(
    const int* rpA, const int* colA, const u16* srcA, const float* scshA, const u16* wtlA,
    const int* rpB, const int* colB, const u16* srcB, const float* scshB, const u16* wtlB,
    const void* root, int root_f32, const float* scshR, const u16* wtr,
    const float* bias, void* out, int out_bf, int N, float* partial) {
  extern __shared__ __align__(16) char smem[];
  const int tid = threadIdx.x;
  const int r0 = blockIdx.x * 32;
  const int nbuf = 1 + (rpB ? 1 : 0) + (root ? 1 : 0);
  u16* smA = (u16*)smem;
  u16* smB = (u16*)(smem + 8192);
  u16* smR = (u16*)(smem + (size_t)(nbuf - 1) * 8192);
  float* bs = (float*)(smem + (size_t)nbuf * 8192);
  if (partial) bs[tid] = 0.f;

  for (int i = tid; i < nbuf * 512; i += 256) {
    int region = i >> 9;
    int t = i & 511;
    int rr = t >> 4, q = t & 15;
    int row = r0 + rr;
    int c0 = q * 8;
    float acc[8];
#pragma unroll
    for (int e = 0; e < 8; ++e) acc[e] = 0.f;

    bool isRoot = root && (region == nbuf - 1);
    if (isRoot) {
      if (row < N) {
        if (root_f32) {
          const float* rp_ = (const float*)root + (size_t)row * 128 + c0;
          f32x4 lo = *(const f32x4*)rp_;
          f32x4 hi = *(const f32x4*)(rp_ + 4);
          acc[0] = lo.x; acc[1] = lo.y; acc[2] = lo.z; acc[3] = lo.w;
          acc[4] = hi.x; acc[5] = hi.y; acc[6] = hi.z; acc[7] = hi.w;
        } else {
          s16x8 v = *(const s16x8*)((const u16*)root + (size_t)row * 128 + c0);
#pragma unroll
          for (int e = 0; e < 8; ++e) acc[e] = bf2f((u16)v[e]);
        }
        if (scshR) {
#pragma unroll
          for (int e = 0; e < 8; ++e)
            acc[e] = fmaxf(acc[e], 0.f) * scshR[c0 + e] + scshR[128 + c0 + e];
        }
      }
      stage_store(smR, rr, q, acc);
    } else {
      const int* rp = (region == 0) ? rpA : rpB;
      const int* col = (region == 0) ? colA : colB;
      const u16* src = (region == 0) ? srcA : srcB;
      const float* scsh = (region == 0) ? scshA : scshB;
      if (row < N) {
        int j0 = rp[row], j1 = rp[row + 1];
        if (scsh) {
          float sc[8], sh[8];
#pragma unroll
          for (int e = 0; e < 8; ++e) { sc[e] = scsh[c0 + e]; sh[e] = scsh[128 + c0 + e]; }
          if (j0 < j1) {
            s16x8 vc = *(const s16x8*)(src + (size_t)col[j0] * 128 + c0);
            for (int j = j0 + 1; j < j1; ++j) {
              s16x8 vn = *(const s16x8*)(src + (size_t)col[j] * 128 + c0);
#pragma unroll
              for (int e = 0; e < 8; ++e)
                acc[e] += fmaxf(bf2f((u16)vc[e]), 0.f) * sc[e] + sh[e];
              vc = vn;
            }
#pragma unroll
            for (int e = 0; e < 8; ++e)
              acc[e] += fmaxf(bf2f((u16)vc[e]), 0.f) * sc[e] + sh[e];
          }
        } else {
          if (j0 < j1) {
            s16x8 vc = *(const s16x8*)(src + (size_t)col[j0] * 128 + c0);
            for (int j = j0 + 1; j < j1; ++j) {
              s16x8 vn = *(const s16x8*)(src + (size_t)col[j] * 128 + c0);
#pragma unroll
              for (int e = 0; e < 8; ++e) acc[e] += bf2f((u16)vc[e]);
              vc = vn;
            }
#pragma unroll
            for (int e = 0; e < 8; ++e) acc[e] += bf2f((u16)vc[e]);
          }
        }
        float inv = 1.0f / fmaxf((float)(j1 - j0), 1.0f);
#pragma unroll
        for (int e = 0; e < 8; ++e) acc[e] *= inv;
      }
      stage_store((region == 0) ? smA : smB, rr, q, acc);
    }
  }
  __syncthreads();

  // ---- MFMA: wave wv -> row-tile m=wv>>1, col-tiles nq..nq+3 ----
  const int lane = tid & 63;
  const int wv = tid >> 6;
  const int mi = lane & 15;
  const int kg = lane >> 4;
  const int m = wv >> 1;
  const int nq = (wv & 1) * 4;
  const int arow = m * 16 + mi;
  const int abase = arow << 8;
  const int amask = (arow & 7) << 4;

  f32x4 acc4[4];
#pragma unroll
  for (int t = 0; t < 4; ++t) acc4[t] = (f32x4){0.f, 0.f, 0.f, 0.f};

#pragma unroll
  for (int kt = 0; kt < 4; ++kt) {
    int k0 = kt * 32 + kg * 8;
    int off = (abase + (k0 << 1)) ^ amask;
    s16x8 afA = *(const s16x8*)((const char*)smA + off);
    s16x8 afB, afR;
    if (rpB) afB = *(const s16x8*)((const char*)smB + off);
    if (root) afR = *(const s16x8*)((const char*)smR + off);
#pragma unroll
    for (int t = 0; t < 4; ++t) {
      int cr = (nq + t) * 16 + mi;
      s16x8 b = *(const s16x8*)(wtlA + cr * 128 + k0);
      acc4[t] = __builtin_amdgcn_mfma_f32_16x16x32_bf16(afA, b, acc4[t], 0, 0, 0);
      if (rpB) {
        s16x8 b2 = *(const s16x8*)(wtlB + cr * 128 + k0);
        acc4[t] = __builtin_amdgcn_mfma_f32_16x16x32_bf16(afB, b2, acc4[t], 0, 0, 0);
      }
      if (root) {
        s16x8 b3 = *(const s16x8*)(wtr + cr * 128 + k0);
        acc4[t] = __builtin_amdgcn_mfma_f32_16x16x32_bf16(afR, b3, acc4[t], 0, 0, 0);
      }
    }
  }

  // ---- epilogue: C/D col=lane&15, row=(lane>>4)*4+reg [m89]; fused BN stats ----
  int rbase = (lane >> 4) << 2;
#pragma unroll
  for (int t = 0; t < 4; ++t) {
    int c = (nq + t) * 16 + mi;
    float bb = bias[c];
    float s = 0.f, q = 0.f;
#pragma unroll
    for (int reg = 0; reg < 4; ++reg) {
      int row = r0 + m * 16 + rbase + reg;
      if (row < N) {
        size_t o = (size_t)row * 128 + c;
        float v = acc4[t][reg] + bb;
        if (out_bf) ((u16*)out)[o] = f2bf(v);
        else        ((float*)out)[o] = v;
        if (partial) {
          float r = fmaxf(v, 0.f);
          s += r;
          q += r * r;
        }
      }
    }
    if (partial) {
      s += __shfl_xor(s, 16); s += __shfl_xor(s, 32);
      q += __shfl_xor(q, 16); q += __shfl_xor(q, 32);
      if (kg == 0) {
        atomicAdd(&bs[c], s);
        atomicAdd(&bs[128 + c], q);
      }
    }
  }
  if (partial) {
    __syncthreads();
    partial[(size_t)blockIdx.x * 256 + tid] = bs[tid];
  }
}

// ---------------- BN finalize: 2-stage partial reduce ----------------
__global__ void g_bnred(const float* partial, int nb, float* p2) {
  int tid = threadIdx.x;  // 256
  float acc = 0.f;
  for (int blk = blockIdx.x; blk < nb; blk += 64)
    acc += partial[(size_t)blk * 256 + tid];
  p2[(size_t)blockIdx.x * 256 + tid] = acc;
}

__global__ void g_bnfin(const float* p2, const float* g, const float* b,
                        float invN, float* scsh) {
  int c = threadIdx.x;  // 128
  float s = 0.f, q = 0.f;
  for (int blk = 0; blk < 64; ++blk) {
    s += p2[(size_t)blk * 256 + c];
    q += p2[(size_t)blk * 256 + 128 + c];
  }
  float m = s * invN;
  float v = q * invN - m * m;
  float sc = rsqrtf(v + 1e-5f) * g[c];
  scsh[c] = sc;
  scsh[128 + c] = b[c] - m * sc;
}

// ---------------- host ----------------
struct Csr { int* rp; int* col; };

static void bn_vF(int nb, const float* g, const float* b, int n,
                  float* partial, float* p2, float* scsh, hipStream_t st) {
  g_bnred<<<64, 256, 0, st>>>(partial, nb, p2);
  g_bnfin<<<1, 128, 0, st>>>(p2, g, b, 1.0f / (float)n, scsh);
}

extern "C" void kernel_launch(void* const* d_in, const int* in_sizes, int n_in,
                              void* d_out, int out_size, void* d_ws, size_t ws_size,
                              hipStream_t stream) {
  const float* x_paper  = (const float*)d_in[0];
  const float* x_author = (const float*)d_in[1];
  const int* e_pp = (const int*)d_in[3];
  const int* e_pa = (const int*)d_in[4];
  const int* e_ap = (const int*)d_in[5];
  const int* e_ai = (const int*)d_in[6];
  const int* e_ia = (const int*)d_in[7];
  const float* Wl  = (const float*)d_in[8];
  const float* bL  = (const float*)d_in[9];
  const float* Wr  = (const float*)d_in[10];
  const float* bng = (const float*)d_in[11];
  const float* bnb = (const float*)d_in[12];

  const int NP = in_sizes[0] / 128;
  const int NA = in_sizes[1] / 128;
  const int NI = in_sizes[2] / 128;
  const int Epp = in_sizes[3] / 2;
  const int Epa = in_sizes[4] / 2;
  const int Eap = in_sizes[5] / 2;
  const int Eai = in_sizes[6] / 2;
  const int Eia = in_sizes[7] / 2;

  const int nbP = (NP + 31) / 32;
  const int nbA = (NA + 31) / 32;
  const int nbI = (NI + 31) / 32;

  const int R = 2 * NP + 2 * NA + NI;
  const long long Eall = (long long)Epp + Epa + Eap + Eai + Eia;

  // ws (~170 MB)
  char* ws = (char*)d_ws;
  size_t off = 0;
  u16* xp   = (u16*)(ws + off);   off += (size_t)NP * 256;
  u16* h_p1 = (u16*)(ws + off);   off += (size_t)NP * 256;
  u16* h_a1 = (u16*)(ws + off);   off += (size_t)NA * 256;
  u16* wt   = (u16*)(ws + off);   off += (size_t)25 * 16384 * 2;
  int* rp_all  = (int*)(ws + off);   off += (size_t)(R + 1) * 4;
  int* col_all = (int*)(ws + off);   off += (size_t)Eall * 4;
  int* dega    = (int*)(ws + off);   off += (size_t)R * 4;
  int* cur     = (int*)(ws + off);   off += (size_t)R * 4;
  int* bsum    = (int*)(ws + off);   off += 1024;
  float* partial = (float*)(ws + off); off += (size_t)nbP * 1024;
  float* p2    = (float*)(ws + off); off += 64 * 1024;
  float* scsh0 = (float*)(ws + off); off += 1024;
  float* scsh1 = (float*)(ws + off); off += 1024;
  float* scsh2 = (float*)(ws + off); off += 1024;
  float* scsh3 = (float*)(ws + off); off += 1024;
  float* scsh4 = (float*)(ws + off); off += 1024;
  float* cb    = (float*)(ws + off); off += 3 * 512;

  Csr cpp; cpp.rp = rp_all;                      cpp.col = col_all;
  Csr cpa; cpa.rp = rp_all + NP;                 cpa.col = col_all;
  Csr cap; cap.rp = rp_all + NP + NA;            cap.col = col_all;
  Csr cai; cai.rp = rp_all + 2 * NP + NA;        cai.col = col_all;
  Csr cia; cia.rp = rp_all + 2 * NP + NA + NI;   cia.col = col_all;

  float* outp = (float*)d_out;
  float* outa = outp + (size_t)NP * 128;
  float* outi = outa + (size_t)NA * 128;
  u16* h_p0 = (u16*)outp;
  u16* h_a0 = (u16*)outa;
  u16* h_i1 = (u16*)outp + (size_t)NP * 128;

  g_wprep<<<nblkF(25 * 16384), 256, 0, stream>>>(Wl, Wr, wt, 25 * 16384);
  g_bprep<<<1, 128, 0, stream>>>(bL, cb);
  g_cvt<<<nblkF((long long)NP * 32), 256, 0, stream>>>(x_paper, xp, (long long)NP * 32);

  Seg s0 = { e_pp, Epp, 0, 0 };
  Seg s1 = { e_pa, Epa, Epp, NP };
  Seg s2 = { e_ap, Eap, Epp + Epa, NP + NA };
  Seg s3 = { e_ai, Eai, Epp + Epa + Eap, 2 * NP + NA };
  Seg s4 = { e_ia, Eia, Epp + Epa + Eap + Eai, 2 * NP + NA + NI };
  HeteroGraphSAGE_52931176955955_kernel<<<nblkF(R), 256, 0, stream>>>((float*)dega, R);
  g_deg5<<<nblkF(Eall), 256, 0, stream>>>(s0, s1, s2, s3, s4, (int)Eall, dega);
  int C = (R + 255) / 256;
  g_bsum<<<256, 256, 0, stream>>>(dega, R, C, bsum);
  g_scan_write<<<256, 256, 0, stream>>>(dega, R, C, bsum, rp_all, cur);
  g_fill5<<<nblkF(Eall), 256, 0, stream>>>(s0, s1, s2, s3, s4, (int)Eall, cur, col_all);

  const float* nof = (const float*)0;
  const int* noi = (const int*)0;
  const u16* nou = (const u16*)0;
  float* nop = (float*)0;

#define WT(i) (wt + (size_t)(i) * 16384)

  // ---- Layer 0 (raw hidden + fused BN stats) ----
  g_sage<<<nbP, 256, 2 * 8192 + 1024, stream>>>(
      cpp.rp, cpp.col, xp, nof, WT(0), noi, noi, nou, nof, nou,
      xp, 0, nof, WT(11), bL + 0 * 128, h_p0, 1, NP, partial);
  bn_vF(nbP, bng + 0 * 128, bnb + 0 * 128, NP, partial, p2, scsh0, stream);
  g_sage<<<nbA, 256, 2 * 8192 + 1024, stream>>>(
      cpa.rp, cpa.col, xp, nof, WT(1), noi, noi, nou, nof, nou,
      x_author, 1, nof, WT(12), bL + 1 * 128, h_a0, 1, NA, partial);
  bn_vF(nbA, bng + 1 * 128, bnb + 1 * 128, NA, partial, p2, scsh1, stream);

  // ---- Layer 1 ----
  g_sage<<<nbP, 256, 3 * 8192 + 1024, stream>>>(          // p1 = pp + ap (dual)
      cpp.rp, cpp.col, h_p0, scsh0, WT(2), cap.rp, cap.col, h_a0, scsh1, WT(4),
      h_p0, 0, scsh0, WT(22), cb, h_p1, 1, NP, partial);
  bn_vF(nbP, bng + 2 * 128, bnb + 2 * 128, NP, partial, p2, scsh2, stream);
  g_sage<<<nbA, 256, 2 * 8192 + 1024, stream>>>(          // a1 = pa
      cpa.rp, cpa.col, h_p0, scsh0, WT(3), noi, noi, nou, nof, nou,
      h_a0, 0, scsh1, WT(14), bL + 3 * 128, h_a1, 1, NA, partial);
  bn_vF(nbA, bng + 3 * 128, bnb + 3 * 128, NA, partial, p2, scsh3, stream);
  g_sage<<<nbI, 256, 1 * 8192 + 1024, stream>>>(          // i1 = ai (no root)
      cai.rp, cai.col, h_a0, scsh1, WT(5), noi, noi, nou, nof, nou,
      (const void*)0, 0, nof, nou, bL + 5 * 128, h_i1, 1, NI, partial);
  bn_vF(nbI, bng + 4 * 128, bnb + 4 * 128, NI, partial, p2, scsh4, stream);

  // ---- Layer 2 (order: a2, i2, then p2 — p2 clobbers h_i1's region) ----
  g_sage<<<nbA, 256, 3 * 8192, stream>>>(                 // a2 = pa + ia (dual)
      cpa.rp, cpa.col, h_p1, scsh2, WT(7), cia.rp, cia.col, h_i1, scsh4, WT(10),
      h_a1, 0, scsh3, WT(24), cb + 256, outa, 0, NA, nop);
  g_sage<<<nbI, 256, 2 * 8192, stream>>>(                 // i2 = ai
      cai.rp, cai.col, h_a1, scsh3, WT(9), noi, noi, nou, nof, nou,
      h_i1, 0, scsh4, WT(20), bL + 9 * 128, outi, 0, NI, nop);
  g_sage<<<nbP, 256, 3 * 8192, stream>>>(                 // p2 = pp + ap (dual)
      cpp.rp, cpp.col, h_p1, scsh2, WT(6), cap.rp, cap.col, h_a1, scsh3, WT(8),
      h_p1, 0, scsh2, WT(23), cb + 128, outp, 0, NP, nop);

#undef WT
  (void)n_in; (void)ws_size; (void)out_size;
}